// Round 1
// baseline (83.022 us; speedup 1.0000x reference)
//
#include <hip/hip_runtime.h>

// spiking coESN: B=2048 samples, L=1024 steps, N_HID=1024.
// R11: STRAIGHT-LINE FAST PATH. R10 proved (closed-form, in-prologue) that no
// RF spike is possible for any sample => output identically zero. R11 removes
// every synchronization from that hot path:
//  - each wave loads the FULL x-row itself (2nd wave's load is an L1/L2 hit,
//    rows are block-private) and max-reduces via __shfl_xor -> no wmax LDS
//    exchange, no barrier.
//  - each wave redundantly evaluates the proof for ALL 1024 units (identical
//    FP ops in both waves -> identical verdict) -> no flag, no 2nd barrier.
//  - LDS staging (xrow, spike masks), per-thread constant loads and the
//    __syncthreads() exist only inside the cold branch.
// Cold path (exact replay from zero state, R6/R8/R9 lineage) is unchanged and
// correct for general inputs. Data-dependent but identical work every call
// on fixed data (graph-capture safe).

#define NH 1024
#define LT 1024

__global__ __launch_bounds__(128)
void coesn_kernel(const float* __restrict__ x,      // (B, L, 1)
                  const float* __restrict__ x2h,    // (1, NH)
                  const float* __restrict__ h2h,    // (NH, NH) row-major
                  const float* __restrict__ bias,   // (NH,)
                  const float* __restrict__ gam,    // (NH,)
                  const float* __restrict__ eps,    // (NH,)
                  const float* __restrict__ sgain,  // (1,)
                  float* __restrict__ out)          // (B, 2*NH)
{
    const int tid  = threadIdx.x;     // 0..127
    const int lane = tid & 63;
    const int w    = tid >> 6;        // wave 0/1 within the sample
    const int b    = blockIdx.x;

    __shared__ float xrow[LT];                     // cold path only
    __shared__ unsigned long long mskL[2][16];     // cold path only

    const float dt  = 0.01f;
    const float dsg = dt * sgain[0];      // dt * spike_gain (hz impulse size)

    // Each wave loads the whole input row: lane holds float4 slots
    // j*64+lane, j=0..3 (256 float4 = 1024 floats). Wave 1 re-reads what
    // wave 0 fetched -> L1/L2 hit, no extra HBM traffic.
    const float4* src = (const float4*)(x + (size_t)b * LT);
    float4 xv[4];
    #pragma unroll
    for (int j = 0; j < 4; ++j) xv[j] = src[j * 64 + lane];

    // Wave-local max of the positive part (identical result in both waves).
    float lm = 0.0f;
    #pragma unroll
    for (int j = 0; j < 4; ++j)
        lm = fmaxf(lm, fmaxf(fmaxf(xv[j].x, xv[j].y), fmaxf(xv[j].z, xv[j].w)));
    #pragma unroll
    for (int off = 1; off < 64; off <<= 1)
        lm = fmaxf(lm, __shfl_xor(lm, off));
    const float mxx = lm;                 // wave-uniform

    // Static no-RF-spike proof, evaluated by EACH wave for ALL 1024 units
    // (16 per lane). Identical arithmetic => identical verdict per wave, so
    // no cross-wave exchange is needed.
    //  1) pre-first-RF-spike recurrent input is 0, so per-unit LIF drive
    //     dt*I <= dtI = dt*bias + max(x,0)*dt*wx (wx >= 0); from vv0=0 /
    //     reset-residual<=dtI the LIF inter-spike interval >= K =
    //     (1-dtI)/dtI - 1.
    //  2) RF pair is a damped linear oscillator: per hz-impulse dsg,
    //     |hy| <= dsg/wd, wd = sqrt(gam - eps^2/4) (checked >= 0.5);
    //     envelope decays e^{-(eps/2)t}; spikes >= K apart =>
    //     max|hy| <= 1.25*dsg / (wd * (1 - e^{-eps*dt*K/2})).
    //  3) bound < 0.75 for ALL units => no RF spike => output exactly zero.
    bool ok = true;
    #pragma unroll
    for (int j = 0; j < 4; ++j) {
        const int f = j * 64 + lane;
        const float4 wx4 = ((const float4*)x2h)[f];
        const float4 bi4 = ((const float4*)bias)[f];
        const float4 ep4 = ((const float4*)eps)[f];
        const float4 ga4 = ((const float4*)gam)[f];
        const float wxv[4] = {wx4.x, wx4.y, wx4.z, wx4.w};
        const float biv[4] = {bi4.x, bi4.y, bi4.z, bi4.w};
        const float epc[4] = {ep4.x, ep4.y, ep4.z, ep4.w};
        const float gac[4] = {ga4.x, ga4.y, ga4.z, ga4.w};
        #pragma unroll
        for (int c = 0; c < 4; ++c) {
            const float dtI = dt * biv[c] + mxx * (dt * wxv[c]);
            const float Ku  = fmaxf((1.0f - dtI) / dtI - 1.0f, 0.0f);
            const float e   = __expf(-0.5f * dt * epc[c] * Ku);
            const float wd2 = gac[c] - 0.25f * epc[c] * epc[c];
            // max|hy| <= 1.25*dsg/(wd*(1-e)) < 0.75 (mul form: no inf/NaN)
            const bool p = (dtI <= 0.0f) ||
                           ((wd2 >= 0.25f) &&
                            (1.25f * dsg < 0.75f * sqrtf(wd2) * (1.0f - e)));
            ok = ok && p;
        }
    }

    float* ob = out + (size_t)b * (2 * NH);

    if (__ballot(!ok) == 0ull) {
        // HOT: no RF spike possible in [0,L] -> rf/ft/fs identically zero.
        // Row = 2*NH floats = 512 float4; each wave stores its half.
        const float4 z = {0.f, 0.f, 0.f, 0.f};
        float4* o4 = (float4*)ob;
        #pragma unroll
        for (int j = 0; j < 4; ++j)
            o4[w * 256 + j * 64 + lane] = z;
        return;
    }

    // ---------------- COLD: full replay from zero state (exact) ------------
    {
        // Stage the row into LDS (each wave writes the half it "owns").
        #pragma unroll
        for (int jj = 0; jj < 2; ++jj) {
            const int j = 2 * w + jj;
            ((float4*)xrow)[j * 64 + lane] = xv[j];
        }
        if (tid < 16) mskL[0][tid] = 0ull;

        // Per-unit constants; float4 index fi = (2w+j)*64 + lane.
        float dwx[8], dbi[8], epv[8], gav[8];
        #pragma unroll
        for (int j = 0; j < 2; ++j) {
            const int fi = (2 * w + j) * 64 + lane;
            float4 t4;
            t4 = ((const float4*)x2h)[fi];
            dwx[4*j+0]=dt*t4.x; dwx[4*j+1]=dt*t4.y; dwx[4*j+2]=dt*t4.z; dwx[4*j+3]=dt*t4.w;
            t4 = ((const float4*)bias)[fi];
            dbi[4*j+0]=dt*t4.x; dbi[4*j+1]=dt*t4.y; dbi[4*j+2]=dt*t4.z; dbi[4*j+3]=dt*t4.w;
            t4 = ((const float4*)eps)[fi];
            epv[4*j+0]=t4.x; epv[4*j+1]=t4.y; epv[4*j+2]=t4.z; epv[4*j+3]=t4.w;
            t4 = ((const float4*)gam)[fi];
            gav[4*j+0]=t4.x; gav[4*j+1]=t4.y; gav[4*j+2]=t4.z; gav[4*j+3]=t4.w;
        }
        __syncthreads();   // xrow + masks visible

        const float cv  = 0.9995f;            // 1 - dt/LIF_TAU_M
        const float dcf = expf(-0.001f);      // exp(-DT/TAU_FILTER)
        const float dcr = expf(-0.04f);       // exp(-DT/TAU_REF)
        float dg[8], cez[8];
        #pragma unroll
        for (int s = 0; s < 8; ++s) {
            dg[s]  = dt * gav[s];
            cez[s] = 1.0f - dt * epv[s];
        }
        float vv[8], hz[8], hy[8], rf[8], ft[8], fs[8];
        #pragma unroll
        for (int s = 0; s < 8; ++s) {
            vv[s]=0.f; hz[s]=0.f; hy[s]=0.f; rf[s]=0.f; ft[s]=0.f; fs[s]=0.f;
        }
        const float4* h2h4 = (const float4*)h2h;

        for (int step = 0; step < LT; ++step) {
            const int p = step & 1;
            const float xt = xrow[step];

            float a[8];
            #pragma unroll
            for (int s = 0; s < 8; ++s) a[s] = 0.f;
            // Fixed unit order: q = (2w'+j')*4 + c ascending, lane ascending.
            #pragma unroll
            for (int q = 0; q < 16; ++q) {
                unsigned long long m = mskL[p][q];
                const int wj = q >> 2;
                const int c  = q & 3;
                while (m) {
                    const int l = __builtin_ctzll(m);
                    m &= (m - 1);
                    const int k = wj * 256 + l * 4 + c;     // spiked unit
                    const size_t rowb = (size_t)k * 256;
                    #pragma unroll
                    for (int j = 0; j < 2; ++j) {
                        const float4 r = h2h4[rowb + (2*w+j)*64 + lane];
                        a[4*j+0] += r.x; a[4*j+1] += r.y;
                        a[4*j+2] += r.z; a[4*j+3] += r.w;
                    }
                }
            }

            #pragma unroll
            for (int s = 0; s < 8; ++s) {
                float t0 = fmaf(xt, dwx[s], dbi[s]);       // dt*(xt*wx + bias)
                t0 = fmaf(dt, a[s], t0);                   // + dt * (s@h2h)
                vv[s] = fmaf(cv, vv[s], t0);
                const bool lc = vv[s] > 1.0f;
                vv[s] = lc ? vv[s] - 1.0f : vv[s];
                const float ks = lc ? dsg : 0.0f;
                const float t1 = fmaf(-dg[s], hy[s], ks);
                hz[s] = fmaf(cez[s], hz[s], t1);
                hy[s] = fmaf(dt, hz[s], hy[s]);
                const bool sc = (hy[s] - rf[s]) > 1.0f;    // RF spike, old ref
                const unsigned long long mm = __ballot(sc);
                if (lane == 0)
                    mskL[p ^ 1][(2*w + (s >> 2)) * 4 + (s & 3)] = mm;
                const float sn = sc ? 1.0f : 0.0f;
                rf[s] = fmaf(dcr, rf[s], sn);
                ft[s] = fmaf(dcf, ft[s], sn);
                fs[s] += ft[s];
            }
            __syncthreads();   // masks visible; prev buffer free for reuse
        }

        const float inv = 1.0f / 1024.0f;
        #pragma unroll
        for (int j = 0; j < 2; ++j) {
            float4 mo = {fs[4*j+0]*inv, fs[4*j+1]*inv, fs[4*j+2]*inv, fs[4*j+3]*inv};
            float4 to = {ft[4*j+0], ft[4*j+1], ft[4*j+2], ft[4*j+3]};
            ((float4*)ob)[(2*w+j)*64 + lane]        = mo;
            ((float4*)(ob + NH))[(2*w+j)*64 + lane] = to;
        }
    }
}

extern "C" void kernel_launch(void* const* d_in, const int* in_sizes, int n_in,
                              void* d_out, int out_size, void* d_ws, size_t ws_size,
                              hipStream_t stream) {
    const float* x     = (const float*)d_in[0];
    const float* x2h   = (const float*)d_in[1];
    const float* h2h   = (const float*)d_in[2];
    const float* bias  = (const float*)d_in[3];
    const float* gam   = (const float*)d_in[4];
    const float* eps   = (const float*)d_in[5];
    const float* sgain = (const float*)d_in[6];
    float* out = (float*)d_out;

    coesn_kernel<<<dim3(2048), dim3(128), 0, stream>>>(
        x, x2h, h2h, bias, gam, eps, sgain, out);
}